// Round 2
// baseline (360.089 us; speedup 1.0000x reference)
//
#include <hip/hip_runtime.h>

typedef unsigned short u16;
typedef unsigned int u32;
typedef __bf16 bf16x4 __attribute__((ext_vector_type(4)));
typedef __bf16 bf16x8 __attribute__((ext_vector_type(8)));
typedef float f32x4 __attribute__((ext_vector_type(4)));

struct __align__(4) U16x2 { u16 x, y; };
struct __align__(8) U16x4 { u16 x, y, z, w; };

#define DEV static __device__ __forceinline__

DEV u16 f2bf(float f) {
  __bf16 h = (__bf16)f;
  return __builtin_bit_cast(u16, h);
}
DEV float bf2f(u16 u) { return __uint_as_float(((u32)u) << 16); }

DEV void gload16(const void* g, void* l) {
  __builtin_amdgcn_global_load_lds((const __attribute__((address_space(1))) char*)g,
                                   (__attribute__((address_space(3))) char*)l, 16, 0, 0);
}

DEV f32x4 mfma16(bf16x8 a, bf16x8 b, f32x4 c) {
  return __builtin_amdgcn_mfma_f32_16x16x32_bf16(a, b, c, 0, 0, 0);
}

// ---------------------------------------------------------------------------
// x fp32 -> bf16, 4 elems/thread
__global__ __launch_bounds__(256) void cvt_x(const float* __restrict__ x, u16* __restrict__ xb) {
  int i = blockIdx.x * 256 + threadIdx.x;
  float4 v = ((const float4*)x)[i];
  U16x4 o;
  o.x = f2bf(v.x); o.y = f2bf(v.y); o.z = f2bf(v.z); o.w = f2bf(v.w);
  ((U16x4*)xb)[i] = o;
}

// ---------------------------------------------------------------------------
// fp32 [R][C] -> bf16 dst[nOff + c][r] (transposed), ldd = R
__global__ __launch_bounds__(256) void tconv(const float* __restrict__ src, u16* __restrict__ dst,
                                             int C, int nOff, int ldd) {
  __shared__ float t[32][33];
  int bx = blockIdx.x, by = blockIdx.y;
  int tx = threadIdx.x, ty = threadIdx.y;
#pragma unroll
  for (int j = 0; j < 4; ++j)
    t[ty + 8 * j][tx] = src[(size_t)(by * 32 + ty + 8 * j) * C + bx * 32 + tx];
  __syncthreads();
#pragma unroll
  for (int j = 0; j < 4; ++j)
    dst[(size_t)(nOff + bx * 32 + ty + 8 * j) * ldd + by * 32 + tx] = f2bf(t[tx][ty + 8 * j]);
}

// ---------------------------------------------------------------------------
// bf16 qkv v-slice [b*2048+s][2560+kh*64+d] -> Vt[(b*8+kh)*64+d][s]
__global__ __launch_bounds__(256) void vtrans(const u16* __restrict__ qkv, u16* __restrict__ Vt) {
  __shared__ u16 t[32][33];
  int bx = blockIdx.x, by = blockIdx.y, bz = blockIdx.z;
  int tx = threadIdx.x, ty = threadIdx.y;
  int b = bz >> 3, kh = bz & 7;
  const u16* src = qkv + (size_t)(b * 2048 + bx * 32) * 3072 + 2560 + kh * 64 + by * 32;
#pragma unroll
  for (int j = 0; j < 4; ++j) t[ty + 8 * j][tx] = src[(size_t)(ty + 8 * j) * 3072 + tx];
  __syncthreads();
  u16* dst = Vt + ((size_t)bz * 64 + by * 32) * 2048 + bx * 32;
#pragma unroll
  for (int j = 0; j < 4; ++j) dst[(size_t)(ty + 8 * j) * 2048 + tx] = t[tx][ty + 8 * j];
}

// ---------------------------------------------------------------------------
// RoPE on q,k heads of qkv[4096][3072]; writes Q[b][h][s][64], K[b][kh][s][64]
__global__ __launch_bounds__(256) void rope_qk(const u16* __restrict__ qkv,
                                               const float* __restrict__ fc,
                                               const float* __restrict__ fs,
                                               u16* __restrict__ Qo, u16* __restrict__ Ko) {
  int t = blockIdx.x * 256 + threadIdx.x;  // 5,242,880 total
  int d2 = t & 31;
  int rest = t >> 5;
  int h40 = rest % 40;
  int bs = rest / 40;  // b*2048 + s
  int s = bs & 2047;
  int b = bs >> 11;
  const u16* src;
  u16* dst;
  if (h40 < 32) {
    src = qkv + (size_t)bs * 3072 + h40 * 64 + 2 * d2;
    dst = Qo + (((size_t)(b * 32 + h40) * 2048 + s) * 64 + 2 * d2);
  } else {
    int kh = h40 - 32;
    src = qkv + (size_t)bs * 3072 + 2048 + kh * 64 + 2 * d2;
    dst = Ko + (((size_t)(b * 8 + kh) * 2048 + s) * 64 + 2 * d2);
  }
  U16x2 v = *(const U16x2*)src;
  float xr = bf2f(v.x), xi = bf2f(v.y);
  float c = fc[s * 32 + d2], sn = fs[s * 32 + d2];
  U16x2 o;
  o.x = f2bf(xr * c - xi * sn);
  o.y = f2bf(xr * sn + xi * c);
  *(U16x2*)dst = o;
}

// ---------------------------------------------------------------------------
// C[M][N] = A[M][K] * BT[N][K]^T  (bf16 in, OutT out). 128x128 tile, BK=64,
// 4 waves (2x2), swizzled LDS, double-buffered global_load_lds staging.
template <typename OutT>
__global__ __launch_bounds__(256, 2) void gemm_bt(const u16* __restrict__ A,
                                                  const u16* __restrict__ BT,
                                                  OutT* __restrict__ C,
                                                  int M, int N, int K) {
  __shared__ __align__(16) char smem[65536];  // As[2]@0, Bs[2]@32768 (16384 each)
  const int tid = threadIdx.x;
  const int lane = tid & 63;
  const int wm = (tid >> 7) & 1, wn = (tid >> 6) & 1;
  const int tm = blockIdx.y, tn = blockIdx.x;
  const int Kb = K * 2;

  f32x4 acc[4][4];
#pragma unroll
  for (int i = 0; i < 4; ++i)
#pragma unroll
    for (int j = 0; j < 4; ++j) acc[i][j] = (f32x4){0.f, 0.f, 0.f, 0.f};

  const char* Ag = (const char*)A + (size_t)tm * 128 * Kb;
  const char* Bg = (const char*)BT + (size_t)tn * 128 * Kb;

  auto stage = [&](int buf, int t) {
#pragma unroll
    for (int i = 0; i < 4; ++i) {
      int vt = i * 256 + tid;
      int row = vt >> 3;
      int cb = (((vt & 7) << 4) ^ ((row & 7) << 4));
      gload16(Ag + (size_t)row * Kb + t * 128 + cb, smem + buf * 16384 + vt * 16);
      gload16(Bg + (size_t)row * Kb + t * 128 + cb, smem + 32768 + buf * 16384 + vt * 16);
    }
  };

  stage(0, 0);
  int cur = 0;
  const int NT = K >> 6;
  for (int t = 0; t < NT; ++t) {
    __syncthreads();
    if (t + 1 < NT) stage(cur ^ 1, t + 1);
    const char* As = smem + cur * 16384;
    const char* Bs = smem + 32768 + cur * 16384;
#pragma unroll
    for (int ks = 0; ks < 2; ++ks) {
      bf16x8 a[4], b[4];
#pragma unroll
      for (int mf = 0; mf < 4; ++mf) {
        int row = wm * 64 + mf * 16 + (lane & 15);
        int cb = (ks * 64 + ((lane >> 4) << 4)) ^ ((row & 7) << 4);
        a[mf] = *(const bf16x8*)(As + row * 128 + cb);
      }
#pragma unroll
      for (int nf = 0; nf < 4; ++nf) {
        int row = wn * 64 + nf * 16 + (lane & 15);
        int cb = (ks * 64 + ((lane >> 4) << 4)) ^ ((row & 7) << 4);
        b[nf] = *(const bf16x8*)(Bs + row * 128 + cb);
      }
#pragma unroll
      for (int mf = 0; mf < 4; ++mf)
#pragma unroll
        for (int nf = 0; nf < 4; ++nf) acc[mf][nf] = mfma16(a[mf], b[nf], acc[mf][nf]);
    }
    cur ^= 1;
  }
#pragma unroll
  for (int mf = 0; mf < 4; ++mf) {
    int row0 = tm * 128 + wm * 64 + mf * 16 + ((lane >> 4) << 2);
#pragma unroll
    for (int nf = 0; nf < 4; ++nf) {
      int col = tn * 128 + wn * 64 + nf * 16 + (lane & 15);
#pragma unroll
      for (int r = 0; r < 4; ++r) {
        float v = acc[mf][nf][r];
        if constexpr (sizeof(OutT) == 4)
          C[(size_t)(row0 + r) * N + col] = v;
        else
          C[(size_t)(row0 + r) * N + col] = f2bf(v);
      }
    }
  }
}

// ---------------------------------------------------------------------------
// Causal GQA flash attention, wave-autonomous rows.
// Block = (qb, h, b): 128 q-rows; wave w owns rows [w*32, w*32+32).
// Softmax stats (m, l) live in registers, replicated across 16-lane groups.
// P tile is wave-private LDS. One barrier per K/V tile (double-buffer).
__global__ __launch_bounds__(256, 2) void attn(const u16* __restrict__ Q,
                                               const u16* __restrict__ Kt,
                                               const u16* __restrict__ Vt,
                                               u16* __restrict__ O) {
  __shared__ __align__(16) char smem[49152];
  // K dbuf: [0,16384)  V dbuf: [16384,32768)  P: [32768,49152) = [128 rows][128 B]

  const int tid = threadIdx.x, lane = tid & 63, w = tid >> 6;
  const int qb = blockIdx.x, h = blockIdx.y, b = blockIdx.z;
  const int kh = h >> 2;

  const char* Qg = (const char*)(Q + (((size_t)(b * 32 + h) * 2048 + qb * 128) * 64));
  const char* Kg = (const char*)(Kt + ((size_t)(b * 8 + kh) * 2048 * 64));
  const char* Vg = (const char*)(Vt + ((size_t)(b * 8 + kh) * 64 * 2048));
  u16* Og = O + ((size_t)(b * 2048 + qb * 128) * 2048 + h * 64);

  // Q fragments: rows w*32 + mf2*16 + (lane&15), k-halves ks
  bf16x8 qf[2][2];
#pragma unroll
  for (int mf2 = 0; mf2 < 2; ++mf2)
#pragma unroll
    for (int ks = 0; ks < 2; ++ks) {
      int row = w * 32 + mf2 * 16 + (lane & 15);
      qf[mf2][ks] = *(const bf16x8*)(Qg + row * 128 + ks * 64 + ((lane >> 4) << 4));
    }

  f32x4 acc[2][4];
#pragma unroll
  for (int i = 0; i < 2; ++i)
#pragma unroll
    for (int j = 0; j < 4; ++j) acc[i][j] = (f32x4){0.f, 0.f, 0.f, 0.f};
  float m_r[2][4], l_r[2][4];
#pragma unroll
  for (int i = 0; i < 2; ++i)
#pragma unroll
    for (int r = 0; r < 4; ++r) { m_r[i][r] = -1e30f; l_r[i][r] = 0.f; }

  auto stageKV = [&](int buf, int kt) {
#pragma unroll
    for (int i = 0; i < 2; ++i) {
      int vt = i * 256 + tid;
      int row = vt >> 3;
      int cb = (((vt & 7) << 4) ^ ((row & 7) << 4));
      gload16(Kg + (size_t)(kt * 64 + row) * 128 + cb, smem + buf * 8192 + vt * 16);
      gload16(Vg + (size_t)row * 4096 + kt * 128 + cb, smem + 16384 + buf * 8192 + vt * 16);
    }
  };

  stageKV(0, 0);
  int cur = 0;
  const int nkt = 2 * qb + 2;
  for (int kt = 0; kt < nkt; ++kt) {
    __syncthreads();  // KV[cur] staged (compiler drains vmcnt before barrier)
    if (kt + 1 < nkt) stageKV(cur ^ 1, kt + 1);  // prefetch; drains at next barrier
    const char* Ks = smem + cur * 8192;
    const char* Vs = smem + 16384 + cur * 8192;

    // QK^T: rows w*32+mf2*16.., cols nf*16..
    f32x4 sv[2][4];
#pragma unroll
    for (int i = 0; i < 2; ++i)
#pragma unroll
      for (int j = 0; j < 4; ++j) sv[i][j] = (f32x4){0.f, 0.f, 0.f, 0.f};
#pragma unroll
    for (int ks = 0; ks < 2; ++ks) {
      bf16x8 kf[4];
#pragma unroll
      for (int nf = 0; nf < 4; ++nf) {
        int row = nf * 16 + (lane & 15);
        int cb = (ks * 64 + ((lane >> 4) << 4)) ^ ((row & 7) << 4);
        kf[nf] = *(const bf16x8*)(Ks + row * 128 + cb);
      }
#pragma unroll
      for (int mf2 = 0; mf2 < 2; ++mf2)
#pragma unroll
        for (int nf = 0; nf < 4; ++nf) sv[mf2][nf] = mfma16(qf[mf2][ks], kf[nf], sv[mf2][nf]);
    }

    // scale + causal mask
    const bool maskt = (kt >= 2 * qb);
#pragma unroll
    for (int mf2 = 0; mf2 < 2; ++mf2)
#pragma unroll
      for (int nf = 0; nf < 4; ++nf)
#pragma unroll
        for (int r = 0; r < 4; ++r) {
          float v = sv[mf2][nf][r] * 0.125f;
          if (maskt) {
            int qg = qb * 128 + w * 32 + mf2 * 16 + ((lane >> 4) << 2) + r;
            int kg = kt * 64 + nf * 16 + (lane & 15);
            if (kg > qg) v = -1e30f;
          }
          sv[mf2][nf][r] = v;
        }

    // per-16-row-fragment softmax, all in registers
#pragma unroll
    for (int mf2 = 0; mf2 < 2; ++mf2) {
      float vm[4];
#pragma unroll
      for (int r = 0; r < 4; ++r)
        vm[r] = fmaxf(fmaxf(sv[mf2][0][r], sv[mf2][1][r]), fmaxf(sv[mf2][2][r], sv[mf2][3][r]));
#pragma unroll
      for (int st = 1; st < 16; st <<= 1)
#pragma unroll
        for (int r = 0; r < 4; ++r) vm[r] = fmaxf(vm[r], __shfl_xor(vm[r], st, 64));
      float mn[4], cr[4];
#pragma unroll
      for (int r = 0; r < 4; ++r) {
        mn[r] = fmaxf(m_r[mf2][r], vm[r]);
        cr[r] = __expf(m_r[mf2][r] - mn[r]);
        m_r[mf2][r] = mn[r];
      }
      // P = exp(S - m_new) -> bf16 into wave-private LDS (swizzled); row sums
      float vs[4] = {0.f, 0.f, 0.f, 0.f};
#pragma unroll
      for (int nf = 0; nf < 4; ++nf)
#pragma unroll
        for (int r = 0; r < 4; ++r) {
          float p = __expf(sv[mf2][nf][r] - mn[r]);
          u16 pb = f2bf(p);
          vs[r] += bf2f(pb);
          int prow = w * 32 + mf2 * 16 + ((lane >> 4) << 2) + r;
          int sw = (prow & 7) << 4;
          int c0 = (nf * 16 + (lane & 15)) * 2;
          *(u16*)(smem + 32768 + prow * 128 + (c0 ^ sw)) = pb;
        }
#pragma unroll
      for (int st = 1; st < 16; st <<= 1)
#pragma unroll
        for (int r = 0; r < 4; ++r) vs[r] += __shfl_xor(vs[r], st, 64);
#pragma unroll
      for (int r = 0; r < 4; ++r) l_r[mf2][r] = l_r[mf2][r] * cr[r] + vs[r];
      // rescale O accumulator (same row mapping as sv/acc)
#pragma unroll
      for (int nf = 0; nf < 4; ++nf)
#pragma unroll
        for (int r = 0; r < 4; ++r) acc[mf2][nf][r] *= cr[r];
    }

    // PV: wave-private P rows, shared V tile. No barrier needed (same-wave LDS order).
#pragma unroll
    for (int ks = 0; ks < 2; ++ks) {
      bf16x8 pa[2], vb[4];
#pragma unroll
      for (int mf2 = 0; mf2 < 2; ++mf2) {
        int prow = w * 32 + mf2 * 16 + (lane & 15);
        int cb = (ks * 64 + ((lane >> 4) << 4)) ^ ((prow & 7) << 4);
        pa[mf2] = *(const bf16x8*)(smem + 32768 + prow * 128 + cb);
      }
#pragma unroll
      for (int nf = 0; nf < 4; ++nf) {
        int vrow = nf * 16 + (lane & 15);
        int cb = (ks * 64 + ((lane >> 4) << 4)) ^ ((vrow & 7) << 4);
        vb[nf] = *(const bf16x8*)(Vs + vrow * 128 + cb);
      }
#pragma unroll
      for (int mf2 = 0; mf2 < 2; ++mf2)
#pragma unroll
        for (int nf = 0; nf < 4; ++nf) acc[mf2][nf] = mfma16(pa[mf2], vb[nf], acc[mf2][nf]);
    }
    cur ^= 1;
  }

#pragma unroll
  for (int mf2 = 0; mf2 < 2; ++mf2)
#pragma unroll
    for (int r = 0; r < 4; ++r) {
      int row = w * 32 + mf2 * 16 + ((lane >> 4) << 2) + r;
      float li = 1.f / l_r[mf2][r];
#pragma unroll
      for (int nf = 0; nf < 4; ++nf)
        Og[(size_t)row * 2048 + nf * 16 + (lane & 15)] = f2bf(acc[mf2][nf][r] * li);
    }
}

// ---------------------------------------------------------------------------
extern "C" void kernel_launch(void* const* d_in, const int* in_sizes, int n_in,
                              void* d_out, int out_size, void* d_ws, size_t ws_size,
                              hipStream_t stream) {
  const float* x = (const float*)d_in[0];
  const float* fc = (const float*)d_in[1];
  const float* fs = (const float*)d_in[2];
  const float* wq = (const float*)d_in[3];
  const float* wk = (const float*)d_in[4];
  const float* wv = (const float*)d_in[5];
  const float* wo = (const float*)d_in[6];
  float* out = (float*)d_out;
  char* ws = (char*)d_ws;

  // Compact workspace layout (60 MB total):
  u16* xb    = (u16*)(ws);                 // [4096][2048] 16 MB  (reused as Q)
  u16* qkv   = (u16*)(ws + 16777216);      // [4096][3072] 24 MB  (reused as O)
  u16* woT   = (u16*)(ws + 41943040);      // [2048][2048]  8 MB
  u16* wqkvT = (u16*)(ws + 50331648);      // [3072][2048] 12 MB (dead after QKV GEMM)
  u16* Kbuf  = (u16*)(ws + 50331648);      // [2][8][2048][64] 4 MB (overlays wqkvT)
  u16* Vtb   = (u16*)(ws + 54525952);      // [2][8][64][2048] 4 MB (overlays wqkvT)
  u16* Qbuf = xb;
  u16* Obuf = qkv;

  dim3 tb(32, 8);
  cvt_x<<<dim3(8192), dim3(256), 0, stream>>>(x, xb);
  tconv<<<dim3(64, 64), tb, 0, stream>>>(wq, wqkvT, 2048, 0, 2048);
  tconv<<<dim3(16, 64), tb, 0, stream>>>(wk, wqkvT, 512, 2048, 2048);
  tconv<<<dim3(16, 64), tb, 0, stream>>>(wv, wqkvT, 512, 2560, 2048);
  tconv<<<dim3(64, 64), tb, 0, stream>>>(wo, woT, 2048, 0, 2048);
  gemm_bt<u16><<<dim3(24, 32), dim3(256), 0, stream>>>(xb, wqkvT, qkv, 4096, 3072, 2048);
  rope_qk<<<dim3(20480), dim3(256), 0, stream>>>(qkv, fc, fs, Qbuf, Kbuf);
  vtrans<<<dim3(64, 2, 16), tb, 0, stream>>>(qkv, Vtb);
  attn<<<dim3(16, 32, 2), dim3(256), 0, stream>>>(Qbuf, Kbuf, Vtb, Obuf);
  gemm_bt<float><<<dim3(16, 32), dim3(256), 0, stream>>>(Obuf, woT, out, 4096, 2048, 2048);
}